// Round 2
// baseline (179457.019 us; speedup 1.0000x reference)
//
#include <hip/hip_runtime.h>
#include <hip/hip_cooperative_groups.h>
#include <cmath>

namespace cg = cooperative_groups;

// JAX PRNG mode: 1 = threefry_partitionable (default in recent JAX),
// 0 = legacy split/random_bits. Flip if tokens are wholesale wrong
// (absmax ~3e4 with int32 output now in place).
#define JAX_PARTITIONABLE 1

#define NBLK 256
#define NTHR 512
#define NLAYER 16
#define DIM 1024
#define VOCAB 32000
#define TPROMPT 128
#define NEVENTS 256
#define TOPK 40

// ---------------- Threefry-2x32 (exact JAX schedule) ----------------
__device__ __forceinline__ void tf2x32(unsigned k0, unsigned k1, unsigned x0, unsigned x1,
                                       unsigned& o0, unsigned& o1) {
  unsigned ks2 = k0 ^ k1 ^ 0x1BD11BDAu;
  x0 += k0; x1 += k1;
#define TFR(r) { x0 += x1; x1 = (x1 << (r)) | (x1 >> (32 - (r))); x1 ^= x0; }
  TFR(13) TFR(15) TFR(26) TFR(6)
  x0 += k1; x1 += ks2 + 1u;
  TFR(17) TFR(29) TFR(16) TFR(24)
  x0 += ks2; x1 += k0 + 2u;
  TFR(13) TFR(15) TFR(26) TFR(6)
  x0 += k0; x1 += k1 + 3u;
  TFR(17) TFR(29) TFR(16) TFR(24)
  x0 += k1; x1 += ks2 + 4u;
  TFR(13) TFR(15) TFR(26) TFR(6)
  x0 += ks2; x1 += k0 + 5u;
#undef TFR
  o0 = x0; o1 = x1;
}

// gumbel(key, v) exactly as jax: -log(-log(uniform(tiny,1)))
__device__ __forceinline__ float gumbel_f(unsigned k0, unsigned k1, unsigned v) {
#pragma clang fp contract(off)
  unsigned bits;
#if JAX_PARTITIONABLE
  unsigned y0, y1; tf2x32(k0, k1, 0u, v, y0, y1);
  bits = y0 ^ y1;
#else
  unsigned y0, y1;
  if (v < 16000u) { tf2x32(k0, k1, v, v + 16000u, y0, y1); bits = y0; }
  else            { tf2x32(k0, k1, v - 16000u, v, y0, y1); bits = y1; }
#endif
  const float TINYF = 1.1754943508222875e-38f;
  float f  = __uint_as_float((bits >> 9) | 0x3f800000u);
  float fl = f - 1.0f;                 // uniform in [0,1)
  float u  = fmaxf(TINYF, fl + TINYF); // jax: floats*(max-min)+min, max(min,.)
  float t1 = (float)log((double)u);    // f32-correctly-rounded log
  float t3 = (float)log((double)(-t1));
  return -t3;
}

// XLA's exact f32 tanh (elemental_ir_emitter rational approx, no FMA)
__device__ __forceinline__ float xla_tanhf(float x) {
#pragma clang fp contract(off)
  const float kMax = 7.90531110763549805f;
  float xc = fminf(fmaxf(x, -kMax), kMax);
  float x2 = xc * xc;
  float num = xc * (4.89352455891786e-03f + x2 * (6.37261928875436e-04f +
              x2 * (1.48572235717979e-05f + x2 * (5.12229709037114e-08f +
              x2 * (-8.60467152213735e-11f + x2 * (2.00018790482477e-13f +
              x2 * (-2.76076847742355e-16f)))))));
  float den = 4.89352518554385e-03f + x2 * (2.26843463243900e-03f +
              x2 * (1.18534705686654e-04f + x2 * (1.19825839466702e-06f)));
  float r = num / den;
  return (fabsf(x) < 0.0004f) ? x : r;
}

// order-isomorphic float<->uint for radix select
__device__ __forceinline__ unsigned f2s(float x) {
  unsigned u = __float_as_uint(x);
  return (u & 0x80000000u) ? ~u : (u | 0x80000000u);
}
__device__ __forceinline__ float s2f(unsigned s) {
  unsigned u = (s & 0x80000000u) ? (s & 0x7fffffffu) : ~s;
  return __uint_as_float(u);
}

// ---------------- phases ----------------
__device__ void sampler_phase(int i, const unsigned* skey, const float* marr,
                              int* counts, int* out, int* misc,
                              unsigned* s_hist, float* s_val, int* s_idx,
                              unsigned* s_pref, int* s_r) {
  int tid = threadIdx.x;
  if (tid == 0) { *s_pref = 0u; *s_r = TOPK; }
  for (int p = 3; p >= 0; --p) {
    if (tid < 256) s_hist[tid] = 0u;
    __syncthreads();
    unsigned pref = *s_pref;
    unsigned hi_mask = (p == 3) ? 0u : (0xFFFFFFFFu << ((p + 1) * 8));
    for (int v = tid; v < VOCAB; v += NTHR) {
      unsigned k = skey[v];
      if ((k & hi_mask) == pref)
        atomicAdd(&s_hist[(k >> (p * 8)) & 255u], 1u);
    }
    __syncthreads();
    if (tid == 0) {
      int r = *s_r;
      int b = 255;
      for (; b > 0; --b) { int c = (int)s_hist[b]; if (r <= c) break; r -= c; }
      *s_pref = pref | ((unsigned)b << (p * 8));
      *s_r = r;
    }
    __syncthreads();
  }
  float kth = s2f(*s_pref);  // 40th largest penalized logit
  float bm = -INFINITY; int bv = 0x7fffffff;
  for (int v = tid; v < VOCAB; v += NTHR) {
    float lv = s2f(skey[v]);
    if (!(lv < kth)) {                 // matches where(l < kth, -1e30, l)
      float mv = marr[v];              // l + gumbel (unmasked dominates -1e30)
      if (mv > bm || (mv == bm && v < bv)) { bm = mv; bv = v; }
    }
  }
  s_val[tid] = bm; s_idx[tid] = bv;
  __syncthreads();
  for (int s = NTHR / 2; s > 0; s >>= 1) {
    if (tid < s) {
      float ov = s_val[tid + s]; int oi = s_idx[tid + s];
      if (ov > s_val[tid] || (ov == s_val[tid] && oi < s_idx[tid])) {
        s_val[tid] = ov; s_idx[tid] = oi;
      }
    }
    __syncthreads();
  }
  if (tid == 0) {
    int tok = s_idx[0];
    counts[tok] += 1;
    out[i] = tok;                      // harness reads d_out as int32
    misc[0] = tok;
    __hip_atomic_fetch_add(misc + 1, 1, __ATOMIC_RELEASE, __HIP_MEMORY_SCOPE_AGENT);
  }
}

__device__ void layer_phase(int blk, int tid, int i, const float* E, const float* Wl,
                            float* ctx, int* misc, float* hs, int* s_tok) {
  if (tid == 0) {
    while (__hip_atomic_load(misc + 1, __ATOMIC_ACQUIRE, __HIP_MEMORY_SCOPE_AGENT) < i + 1)
      __builtin_amdgcn_s_sleep(4);
    *s_tok = misc[0];
  }
  __syncthreads();
  int tok = *s_tok;
  const float* erow = E + (size_t)tok * DIM;
  for (int d = tid; d < DIM; d += NTHR) hs[d] = erow[d];
  __syncthreads();
  int wv = tid >> 6, lane = tid & 63, c = lane >> 3, eL = lane & 7;
  int l = blk >> 4;
  int e = ((blk & 15) << 6) + wv * 8 + eL;
  const float* wl = Wl + (size_t)l * (DIM * DIM) + e;
  double acc = 0.0;
#pragma unroll 8
  for (int j = 0; j < 128; ++j) {
    int jj = (j + 4 * c) & 127;          // bank-conflict stagger
    int d = (c << 7) + jj;
    acc = fma((double)hs[d], (double)wl[(size_t)d * DIM], acc);
  }
  acc += __shfl_xor(acc, 8);
  acc += __shfl_xor(acc, 16);
  acc += __shfl_xor(acc, 32);
  if (c == 0) {
    float a = (float)acc;
    float sv = a + ctx[l * DIM + e];
    ctx[l * DIM + e] = xla_tanhf(sv);
  }
  __syncthreads();  // drain ctx stores (compiler emits vmcnt(0) before barrier)
  if (l == 15 && tid == 0)
    __hip_atomic_fetch_add(misc + 2, 1, __ATOMIC_RELEASE, __HIP_MEMORY_SCOPE_AGENT);
}

__device__ void logits_phase(int blk, int tid, int s, int gate, const float* Wo,
                             const float* ctx, const float* temp_p, const float* pen_p,
                             const int* counts, const unsigned* k256,
                             unsigned* skey, float* marr, int* misc, float* hs) {
  if (tid == 0) {
    while (__hip_atomic_load(misc + 2, __ATOMIC_ACQUIRE, __HIP_MEMORY_SCOPE_AGENT) < gate)
      __builtin_amdgcn_s_sleep(4);
  }
  __syncthreads();
  for (int d = tid; d < DIM; d += NTHR) hs[d] = ctx[15 * DIM + d];
  __syncthreads();
  int wv = tid >> 6, lane = tid & 63, c = lane >> 4, vL = lane & 15;
  int v = blk * 128 + wv * 16 + vL;
  const float* wcol = Wo + v;
  double acc = 0.0;
#pragma unroll 8
  for (int j = 0; j < 256; ++j) {
    int jj = (j + 8 * c) & 255;          // bank-conflict stagger
    int d = (c << 8) + jj;
    acc = fma((double)hs[d], (double)wcol[(size_t)d * VOCAB], acc);
  }
  acc += __shfl_xor(acc, 16);
  acc += __shfl_xor(acc, 32);
  if (c == 0) {
#pragma clang fp contract(off)
    float lg = (float)acc;
    float l1 = lg / (*temp_p);
    if (counts[v] > 0) l1 = l1 / (*pen_p);
    skey[v] = f2s(l1);
    float g = gumbel_f(k256[2 * s], k256[2 * s + 1], (unsigned)v);
    marr[v] = l1 + g;
  }
}

// ---------------- persistent cooperative kernel ----------------
__global__ void __launch_bounds__(NTHR, 2) tfxl_kernel(
    const int* __restrict__ ids, const float* __restrict__ E,
    const float* __restrict__ Wl, const float* __restrict__ Wo,
    const float* __restrict__ mems, const int* __restrict__ tcin,
    const float* __restrict__ temp_p, const float* __restrict__ pen_p,
    int* __restrict__ out,
    float* __restrict__ Ht, float* __restrict__ ctx,
    unsigned* __restrict__ skey, float* __restrict__ marr,
    int* __restrict__ counts, unsigned* __restrict__ k256,
    int* __restrict__ misc) {
  cg::grid_group grid = cg::this_grid();
  const int tid = threadIdx.x;
  const int blk = blockIdx.x;

  __shared__ float hs[DIM];
  __shared__ unsigned s_hist[256];
  __shared__ float s_val[NTHR];
  __shared__ int s_idx[NTHR];
  __shared__ float sc[64 * 129];   // prompt scan tile, stride 129 vs bank conflicts
  __shared__ unsigned s_pref;
  __shared__ int s_r;
  __shared__ int s_tok;

  // ---- P0: init Ht (transposed prompt embeddings), ctx, counts, step keys ----
  {
    int g = blk * NTHR + tid;            // 0..131071 == 1024*128
    int t = g & 127, d = g >> 7;
    Ht[d * 128 + t] = E[(size_t)ids[t] * DIM + d];
    if (g < NLAYER * DIM) {
      int l = g >> 10, e = g & 1023;
      ctx[g] = mems[((size_t)l * 512 + 511) * DIM + e];  // mems[:, -1]
    }
    if (g < VOCAB) counts[g] = tcin[g];
    if (g < NEVENTS) {
#if JAX_PARTITIONABLE
      unsigned y0, y1; tf2x32(0u, 42u, 0u, (unsigned)g, y0, y1);
      k256[2 * g] = y0; k256[2 * g + 1] = y1;
#else
      unsigned y0, y1, z0, z1;
      if (g < 128) {
        tf2x32(0u, 42u, (unsigned)(2 * g),     (unsigned)(2 * g + 256), y0, y1);
        tf2x32(0u, 42u, (unsigned)(2 * g + 1), (unsigned)(2 * g + 257), z0, z1);
        k256[2 * g] = y0; k256[2 * g + 1] = z0;
      } else {
        tf2x32(0u, 42u, (unsigned)(2 * g - 256), (unsigned)(2 * g),     y0, y1);
        tf2x32(0u, 42u, (unsigned)(2 * g - 255), (unsigned)(2 * g + 1), z0, z1);
        k256[2 * g] = y1; k256[2 * g + 1] = z1;
      }
#endif
    }
    if (g < 16) misc[g] = 0;
  }
  grid.sync();

  // ---- prompt: fully block-local. Block owns (layer l, 64 e-cols).
  //      GEMM all 128 t into LDS, then sequential tanh scan in-block. ----
  {
    int l = blk >> 4, e0 = (blk & 15) << 6;
    int eL = tid & 63, tg = tid >> 6;        // tg: 8 groups x 16 t
    int e = e0 + eL;
    const float* wl = Wl + (size_t)l * (DIM * DIM) + e;
    const float* hbase = Ht + tg * 16;
    double acc[16];
#pragma unroll
    for (int k = 0; k < 16; ++k) acc[k] = 0.0;
    for (int d = 0; d < DIM; ++d) {
      float w = wl[(size_t)d * DIM];
      const float* hrow = hbase + d * 128;
#pragma unroll
      for (int k = 0; k < 16; ++k)
        acc[k] = fma((double)hrow[k], (double)w, acc[k]);
    }
#pragma unroll
    for (int k = 0; k < 16; ++k)
      sc[eL * 129 + tg * 16 + k] = (float)acc[k];
    __syncthreads();
    if (tid < 64) {
      float s = ctx[l * DIM + e0 + tid];
      for (int t = 0; t < TPROMPT; ++t)
        s = xla_tanhf(sc[tid * 129 + t] + s);
      ctx[l * DIM + e0 + tid] = s;
    }
    __syncthreads();
  }
  grid.sync();

  // ---- pred_logits + prep for sample 0 (gate 0 = no wait) ----
  if (blk < 250)
    logits_phase(blk, tid, 0, 0, Wo, ctx, temp_p, pen_p, counts, k256, skey, marr, misc, hs);
  grid.sync();

  // ---- generation loop: sample -> layers -> logits(+prep next) ----
  for (int i = 0; i < NEVENTS; ++i) {
    if (blk == 0)
      sampler_phase(i, skey, marr, counts, out, misc, s_hist, s_val, s_idx, &s_pref, &s_r);
    if (i == NEVENTS - 1) break;         // uniform: last model step is dead code
    layer_phase(blk, tid, i, E, Wl, ctx, misc, hs, &s_tok);
    if (blk < 250)
      logits_phase(blk, tid, i + 1, 16 * (i + 1), Wo, ctx, temp_p, pen_p,
                   counts, k256, skey, marr, misc, hs);
    grid.sync();
  }
}

extern "C" void kernel_launch(void* const* d_in, const int* in_sizes, int n_in,
                              void* d_out, int out_size, void* d_ws, size_t ws_size,
                              hipStream_t stream) {
  const int*   ids  = (const int*)d_in[0];
  const float* E    = (const float*)d_in[1];
  const float* Wl   = (const float*)d_in[2];
  const float* Wo   = (const float*)d_in[3];
  const float* mems = (const float*)d_in[4];
  const int*   tcin = (const int*)d_in[5];
  const float* temp = (const float*)d_in[6];
  const float* pen  = (const float*)d_in[7];
  int* out = (int*)d_out;                // int64 ref output -> int32 buffer

  char* ws = (char*)d_ws;
  float*    Ht     = (float*)(ws + 0);        // 1024*128 f32 = 512KB
  float*    ctx    = (float*)(ws + 524288);   // 16*1024 f32 = 64KB
  unsigned* skey   = (unsigned*)(ws + 589824);// 32000 u32 (pad to 128KB)
  float*    marr   = (float*)(ws + 720896);   // 32000 f32
  int*      counts = (int*)(ws + 851968);     // 32000 i32
  unsigned* k256   = (unsigned*)(ws + 979968);// 256*2 u32
  int*      misc   = (int*)(ws + 982016);     // flags
  // total < 1 MB

  void* args[] = { &ids, &E, &Wl, &Wo, &mems, &tcin, &temp, &pen, &out,
                   &Ht, &ctx, &skey, &marr, &counts, &k256, &misc };
  hipLaunchCooperativeKernel((const void*)tfxl_kernel, dim3(NBLK), dim3(NTHR),
                             (void**)args, 0, stream);
}